// Round 5
// baseline (201.789 us; speedup 1.0000x reference)
//
#include <hip/hip_runtime.h>
#include <stdint.h>

#define BSH (32 * 128 * 128)

typedef __attribute__((ext_vector_type(8))) __bf16 bf16x8;
typedef __attribute__((ext_vector_type(4))) float f32x4;

__device__ __forceinline__ unsigned short f2bf(float f) {
  union { float f; unsigned u; } v; v.f = f;
  return (unsigned short)((v.u + 0x7FFFu + ((v.u >> 16) & 1u)) >> 16);
}

__device__ __forceinline__ float fast_exp2(float x) {
#if __has_builtin(__builtin_amdgcn_exp2f)
  return __builtin_amdgcn_exp2f(x);
#else
  float r; asm("v_exp_f32 %0, %1" : "=v"(r) : "v"(x)); return r;
#endif
}
__device__ __forceinline__ float fast_rcp(float x) {
#if __has_builtin(__builtin_amdgcn_rcpf)
  return __builtin_amdgcn_rcpf(x);
#else
  float r; asm("v_rcp_f32 %0, %1" : "=v"(r) : "v"(x)); return r;
#endif
}

// tanh-form GELU (MLP path; ~3e-3 max err vs exact erf GELU).
__device__ __forceinline__ float gelu_f(float y) {
  float u = y * y;
  float p = __builtin_fmaf(u, 0.044715f, 1.0f) * y;
  float w = fast_exp2(p * 2.30220787f);
  return y - y * fast_rcp(1.0f + w);
}

// XCD-pinned jg schedule (assumes round-robin bid->XCD via bid&7): XCD x owns
// jg in {x, 15-x, 16+x, 31-x}; per-XCD W1Tc working set ~1.6 MB < 4 MB L2.
__device__ __forceinline__ int jg_of(int x, int cls) {
  return cls == 0 ? x : cls == 1 ? 15 - x : cls == 2 ? 16 + x : 31 - x;
}

// ---------------------------------------------------------------------------
// Chunked k-major layout: tensor [row][k] stored as chunk(kq,row) =
// base + (kq*128 + row)*8 bf16 (16 B). MFMA fragment read = one
// global_load_dwordx4, 256 B contiguous per quad.
// ---------------------------------------------------------------------------
__device__ __forceinline__ void transpose_block_c(const float* __restrict__ src,
                                                  unsigned short* __restrict__ dst,
                                                  unsigned short* lds) {
  const int tid = threadIdx.x;
  const float4* s4 = (const float4*)src;
#pragma unroll
  for (int it = 0; it < 16; ++it) {
    int i4 = tid + it * 256;
    float4 v = s4[i4];
    int s = i4 >> 5;
    int t0 = (i4 * 4) & 127;
    int sc = s >> 3, se = s & 7;
#pragma unroll
    for (int e = 0; e < 4; ++e) {
      int t = t0 + e;
      lds[t * 136 + ((sc ^ ((t >> 2) & 7)) << 3) + se] = f2bf(((const float*)&v)[e]);
    }
  }
  __syncthreads();
#pragma unroll
  for (int it = 0; it < 8; ++it) {
    int c = tid + it * 256;
    int tr = c >> 4, sc = c & 15;
    uint4 d = *(const uint4*)(lds + tr * 136 + ((sc ^ ((tr >> 2) & 7)) << 3));
    *(uint4*)(dst + (sc * 128 + tr) * 8) = d;
  }
}

__global__ __launch_bounds__(256) void prepass_kernel(
    const float* __restrict__ W1, const float* __restrict__ trend2,
    const float* __restrict__ Wm1, const float* __restrict__ Wm2,
    unsigned short* __restrict__ W1Tc, unsigned short* __restrict__ T2c,
    unsigned short* __restrict__ Wm1c, unsigned short* __restrict__ Wm2c,
    float* __restrict__ out2) {
  __shared__ unsigned short lds[128 * 136];
  const int bid = blockIdx.x;
  if (bid < 256) {  // W1[stage][j][s][t] -> chunks (kq_s, t), XCD-pinned j map
    int x = bid & 7, r = bid >> 3;
    int stage = r >> 4, rr = r & 15;
    int j = jg_of(x, rr >> 2) * 4 + (rr & 3);
    int blk = stage * 128 + j;
    transpose_block_c(W1 + blk * 16384, W1Tc + blk * 16384, lds);
  } else if (bid < 288) {  // trend2[b][s][h] -> chunks (kq_s, h) + fp32 copy
    const int b = bid - 256;
    transpose_block_c(trend2 + b * 16384, T2c + b * 16384, lds);
    const float4* s4 = (const float4*)(trend2 + b * 16384);
    float4* d4 = (float4*)(out2 + b * 16384);
#pragma unroll
    for (int it = 0; it < 16; ++it)
      d4[threadIdx.x + it * 256] = s4[threadIdx.x + it * 256];
  } else if (bid == 288) {
    transpose_block_c(Wm1, Wm1c, lds);
  } else {
    transpose_block_c(Wm2, Wm2c, lds);
  }
}

// ---------------------------------------------------------------------------
// Fused mix+MLP v2: block = (jg of 4 j, b), grid 1024, XCD-pinned jg.
// k-loop restructured vs R4:
//   - jj processed in PAIRS (two sequential k-loops): acc = 32 VGPR, total
//     live ~110 < 128 -> spill-free at __launch_bounds__(256,4).
//   - next k-step's 6 fragments prefetched before the current step's MFMAs
//     consume theirs -> one full k-step of global loads always in flight.
// ---------------------------------------------------------------------------
__global__ __launch_bounds__(256, 4) void mix_fused_kernel(
    const unsigned short* __restrict__ XTc,   // [32] chunks (kq_s, h)
    const unsigned short* __restrict__ W1Tj,  // [128] chunks (kq_s, t), stage
    const float* __restrict__ b1j,            // [128][128] (j, t)
    const float* __restrict__ W2j,            // [128][128] (j, t)
    const float* __restrict__ b2j,            // [128]
    const float* __restrict__ trendR,         // [32][128][128] fp32 residual
    const unsigned short* __restrict__ Wm1c,  // chunks (kq_in, out)
    const unsigned short* __restrict__ Wm2c,
    const float* __restrict__ bm1,
    const float* __restrict__ bm2,
    float* __restrict__ outF,                 // [32][128][128] fp32 (MLP out)
    unsigned short* __restrict__ outTc,       // [32] chunks (kq_s, h) or null
    const int write_t) {
  __shared__ float res_ws[4][4][64];
  __shared__ __align__(16) unsigned short xa[16 * 128];  // MLP A-tile chunks
  __shared__ __align__(16) unsigned short U[16 * 128];   // GEMM1->2 bounce
  const int bid = blockIdx.x;
  const int x = bid & 7;
  const int i = bid >> 3;
  const int b = i & 31;
  const int jg = jg_of(x, i >> 5);
  const int j0 = jg * 4;
  const int tid = threadIdx.x;
  const int wave = tid >> 6;
  const int lane = tid & 63;
  const int lane15 = lane & 15;
  const int quad = lane >> 4;

  {  // zero the padded tiles (rows 4-15 must be 0 for the MFMA MLP)
    uint4 z = {0, 0, 0, 0};
    ((uint4*)xa)[tid] = z;
    ((uint4*)U)[tid] = z;
  }

  const int ntiles = (j0 >> 4) + 1;  // t-tiles with t <= j
  const int ksteps = (j0 >> 5) + 1;  // k 32-steps with s <= j
  const unsigned short* Bb = XTc + b * 16384;
  const unsigned short* A0 = W1Tj + j0 * 16384;
  const float C = -2.45546937f;  // -1.702 * log2(e)

#pragma unroll
  for (int p = 0; p < 2; ++p) {
    float psum[4][4];
#pragma unroll
    for (int jj = 0; jj < 4; ++jj)
#pragma unroll
      for (int ni = 0; ni < 4; ++ni) psum[jj][ni] = 0.f;

#pragma unroll
    for (int q = 0; q < 2; ++q) {
      const int mt = wave + q * 4;
      if (mt < ntiles) {
        // base pointers (in shorts); fragment = base + kq*1024
        const unsigned short* bp0 = Bb + (p * 64 + lane15) * 8;
        const unsigned short* ap0 = A0 + (mt * 16 + lane15) * 8;
        const int tb = mt * 16 + quad * 4;
#pragma unroll
        for (int pr = 0; pr < 2; ++pr) {
          const unsigned short* aP = ap0 + (pr * 2) * 16384;
          f32x4 acc[2][4];
#pragma unroll
          for (int jl = 0; jl < 2; ++jl)
#pragma unroll
            for (int ni = 0; ni < 4; ++ni) {
              f32x4 z = {0.f, 0.f, 0.f, 0.f};
              acc[jl][ni] = z;
            }
          // preload k-step 0
          int kq = quad;
          bf16x8 ac0 = *(const bf16x8*)(aP + kq * 1024);
          bf16x8 ac1 = *(const bf16x8*)(aP + 16384 + kq * 1024);
          bf16x8 bc0 = *(const bf16x8*)(bp0 + kq * 1024);
          bf16x8 bc1 = *(const bf16x8*)(bp0 + kq * 1024 + 128);
          bf16x8 bc2 = *(const bf16x8*)(bp0 + kq * 1024 + 256);
          bf16x8 bc3 = *(const bf16x8*)(bp0 + kq * 1024 + 384);
          for (int ks = 0;;) {
            const bool more = (ks + 1 < ksteps);
            bf16x8 an0, an1, bn0, bn1, bn2, bn3;
            if (more) {  // prefetch next k-step while MFMAs consume current
              const int k2 = kq + 4;
              an0 = *(const bf16x8*)(aP + k2 * 1024);
              an1 = *(const bf16x8*)(aP + 16384 + k2 * 1024);
              bn0 = *(const bf16x8*)(bp0 + k2 * 1024);
              bn1 = *(const bf16x8*)(bp0 + k2 * 1024 + 128);
              bn2 = *(const bf16x8*)(bp0 + k2 * 1024 + 256);
              bn3 = *(const bf16x8*)(bp0 + k2 * 1024 + 384);
            }
            acc[0][0] = __builtin_amdgcn_mfma_f32_16x16x32_bf16(ac0, bc0, acc[0][0], 0, 0, 0);
            acc[1][0] = __builtin_amdgcn_mfma_f32_16x16x32_bf16(ac1, bc0, acc[1][0], 0, 0, 0);
            acc[0][1] = __builtin_amdgcn_mfma_f32_16x16x32_bf16(ac0, bc1, acc[0][1], 0, 0, 0);
            acc[1][1] = __builtin_amdgcn_mfma_f32_16x16x32_bf16(ac1, bc1, acc[1][1], 0, 0, 0);
            acc[0][2] = __builtin_amdgcn_mfma_f32_16x16x32_bf16(ac0, bc2, acc[0][2], 0, 0, 0);
            acc[1][2] = __builtin_amdgcn_mfma_f32_16x16x32_bf16(ac1, bc2, acc[1][2], 0, 0, 0);
            acc[0][3] = __builtin_amdgcn_mfma_f32_16x16x32_bf16(ac0, bc3, acc[0][3], 0, 0, 0);
            acc[1][3] = __builtin_amdgcn_mfma_f32_16x16x32_bf16(ac1, bc3, acc[1][3], 0, 0, 0);
            ++ks;
            if (!more) break;
            kq += 4;
            ac0 = an0; ac1 = an1;
            bc0 = bn0; bc1 = bn1; bc2 = bn2; bc3 = bn3;
          }
          // epilogue for this jj-pair
#pragma unroll
          for (int jl = 0; jl < 2; ++jl) {
            const int jj = pr * 2 + jl;
            const int j = j0 + jj;
            float4 b1v = *(const float4*)(b1j + j * 128 + tb);
            float4 w2v = *(const float4*)(W2j + j * 128 + tb);
#pragma unroll
            for (int r = 0; r < 4; ++r) {
              float b1r = ((const float*)&b1v)[r];
              float w2r = ((const float*)&w2v)[r];
              float cb = C * b1r;
              float bw = b1r * w2r;
#pragma unroll
              for (int ni = 0; ni < 4; ++ni) {
                float a = acc[jl][ni][r];
                float m = __builtin_fmaf(a, C, cb);
                float e = fast_exp2(m);
                float rr2 = fast_rcp(1.0f + e);
                float yw = __builtin_fmaf(a, w2r, bw);
                psum[jj][ni] = __builtin_fmaf(yw, rr2, psum[jj][ni]);
              }
            }
          }
        }
      }
    }
#pragma unroll
    for (int jj = 0; jj < 4; ++jj)
#pragma unroll
      for (int ni = 0; ni < 4; ++ni) {
        float v = psum[jj][ni];
        v += __shfl_xor(v, 16, 64);
        v += __shfl_xor(v, 32, 64);
        psum[jj][ni] = v;
      }
#pragma unroll
    for (int jj = 0; jj < 4; ++jj)
      res_ws[wave][jj][quad * 16 + lane15] = psum[jj][quad];
    __syncthreads();
    {  // combine + residual -> bf16 A-tile row jj, k=h chunks
      const int jj = tid >> 6;
      const int hh = tid & 63;
      const int j = j0 + jj;
      const int h = p * 64 + hh;
      float v = res_ws[0][jj][hh] + res_ws[1][jj][hh] +
                res_ws[2][jj][hh] + res_ws[3][jj][hh] +
                b2j[j] + trendR[(b * 128 + j) * 128 + h];
      xa[((h >> 3) * 16 + jj) * 8 + (h & 7)] = f2bf(v);
    }
    __syncthreads();
  }

  // ---- fused MLP on the block's 4 rows (16-row padded MFMA tile) ----
  f32x4 acc2[2];
  { f32x4 z = {0.f, 0.f, 0.f, 0.f}; acc2[0] = z; acc2[1] = z; }
#pragma unroll
  for (int ks = 0; ks < 4; ++ks) {  // GEMM1: x @ Wm1
    int kq = ks * 4 + quad;
    bf16x8 a = *(const bf16x8*)(xa + (kq * 16 + lane15) * 8);
    bf16x8 w0 = *(const bf16x8*)(Wm1c + (kq * 128 + (wave * 2 + 0) * 16 + lane15) * 8);
    bf16x8 w1 = *(const bf16x8*)(Wm1c + (kq * 128 + (wave * 2 + 1) * 16 + lane15) * 8);
    acc2[0] = __builtin_amdgcn_mfma_f32_16x16x32_bf16(a, w0, acc2[0], 0, 0, 0);
    acc2[1] = __builtin_amdgcn_mfma_f32_16x16x32_bf16(a, w1, acc2[1], 0, 0, 0);
  }
  if (quad == 0) {  // rows 0-3 live in quad 0; bias+gelu -> U A-tile
#pragma unroll
    for (int nt = 0; nt < 2; ++nt) {
      int o = (wave * 2 + nt) * 16 + lane15;
      float bv = bm1[o];
#pragma unroll
      for (int r = 0; r < 4; ++r) {
        float g = gelu_f(acc2[nt][r] + bv);
        U[((o >> 3) * 16 + r) * 8 + (o & 7)] = f2bf(g);
      }
    }
  }
  __syncthreads();
  { f32x4 z = {0.f, 0.f, 0.f, 0.f}; acc2[0] = z; acc2[1] = z; }
#pragma unroll
  for (int ks = 0; ks < 4; ++ks) {  // GEMM2: u @ Wm2
    int kq = ks * 4 + quad;
    bf16x8 a = *(const bf16x8*)(U + (kq * 16 + lane15) * 8);
    bf16x8 w0 = *(const bf16x8*)(Wm2c + (kq * 128 + (wave * 2 + 0) * 16 + lane15) * 8);
    bf16x8 w1 = *(const bf16x8*)(Wm2c + (kq * 128 + (wave * 2 + 1) * 16 + lane15) * 8);
    acc2[0] = __builtin_amdgcn_mfma_f32_16x16x32_bf16(a, w0, acc2[0], 0, 0, 0);
    acc2[1] = __builtin_amdgcn_mfma_f32_16x16x32_bf16(a, w1, acc2[1], 0, 0, 0);
  }
  if (quad == 0) {  // epilogue: fp32 out + optional chunked bf16 half-chunks
#pragma unroll
    for (int nt = 0; nt < 2; ++nt) {
      int o = (wave * 2 + nt) * 16 + lane15;
      float bv = bm2[o];
      unsigned short tmp4[4] __attribute__((aligned(8)));
#pragma unroll
      for (int r = 0; r < 4; ++r) {
        float v = acc2[nt][r] + bv;
        outF[b * 16384 + (j0 + r) * 128 + o] = v;
        tmp4[r] = f2bf(v);
      }
      if (write_t)
        *(uint2*)(outTc + b * 16384 + ((j0 >> 3) * 128 + o) * 8 + (j0 & 7)) =
            *(const uint2*)tmp4;
    }
  }
}

// ---------------------------------------------------------------------------
extern "C" void kernel_launch(void* const* d_in, const int* in_sizes, int n_in,
                              void* d_out, int out_size, void* d_ws, size_t ws_size,
                              hipStream_t stream) {
  (void)in_sizes; (void)n_in; (void)out_size; (void)ws_size;
  const float* trend0 = (const float*)d_in[0];
  const float* trend1 = (const float*)d_in[1];
  const float* trend2 = (const float*)d_in[2];
  const float* W1  = (const float*)d_in[3];
  const float* b1  = (const float*)d_in[4];
  const float* W2  = (const float*)d_in[5];
  const float* b2  = (const float*)d_in[6];
  const float* Wm1 = (const float*)d_in[7];
  const float* bm1 = (const float*)d_in[8];
  const float* Wm2 = (const float*)d_in[9];
  const float* bm2 = (const float*)d_in[10];
  float* out = (float*)d_out;
  char* ws = (char*)d_ws;

  unsigned short* W1Tc = (unsigned short*)(ws);             // 8.39 MB (2 stages)
  unsigned short* T2c  = (unsigned short*)(ws + 8388608);   // 1 MB
  unsigned short* A1Tc = (unsigned short*)(ws + 9437184);   // 1 MB
  unsigned short* Wm1c = (unsigned short*)(ws + 10485760);  // 32 KB
  unsigned short* Wm2c = (unsigned short*)(ws + 10518528);  // 32 KB

  // outputs: [A2 | A1 | trend2]
  prepass_kernel<<<290, 256, 0, stream>>>(W1, trend2, Wm1, Wm2,
                                          W1Tc, T2c, Wm1c, Wm2c, out + 2 * BSH);
  // stage 0: X = trend2, residual = trend1 -> A1 (d_out[1]) + A1Tc chunks
  mix_fused_kernel<<<1024, 256, 0, stream>>>(
      T2c, W1Tc, b1, W2, b2, trend1, Wm1c, Wm2c, bm1, bm2,
      out + BSH, A1Tc, 1);
  // stage 1: X = A1, residual = trend0 -> A2 (d_out[0])
  mix_fused_kernel<<<1024, 256, 0, stream>>>(
      A1Tc, W1Tc + 128 * 16384, b1 + 16384, W2 + 16384, b2 + 128, trend0,
      Wm1c, Wm2c, bm1, bm2, out, (unsigned short*)nullptr, 0);
}

// Round 6
// 146.196 us; speedup vs baseline: 1.3803x; 1.3803x over previous
//
#include <hip/hip_runtime.h>
#include <stdint.h>

#define BSH (32 * 128 * 128)

typedef __attribute__((ext_vector_type(8))) __bf16 bf16x8;
typedef __attribute__((ext_vector_type(4))) float f32x4;

__device__ __forceinline__ unsigned short f2bf(float f) {
  union { float f; unsigned u; } v; v.f = f;
  return (unsigned short)((v.u + 0x7FFFu + ((v.u >> 16) & 1u)) >> 16);
}

__device__ __forceinline__ float fast_exp2(float x) {
#if __has_builtin(__builtin_amdgcn_exp2f)
  return __builtin_amdgcn_exp2f(x);
#else
  float r; asm("v_exp_f32 %0, %1" : "=v"(r) : "v"(x)); return r;
#endif
}
__device__ __forceinline__ float fast_rcp(float x) {
#if __has_builtin(__builtin_amdgcn_rcpf)
  return __builtin_amdgcn_rcpf(x);
#else
  float r; asm("v_rcp_f32 %0, %1" : "=v"(r) : "v"(x)); return r;
#endif
}

// tanh-form GELU (MLP path; ~3e-3 max err vs exact erf GELU).
__device__ __forceinline__ float gelu_f(float y) {
  float u = y * y;
  float p = __builtin_fmaf(u, 0.044715f, 1.0f) * y;
  float w = fast_exp2(p * 2.30220787f);
  return y - y * fast_rcp(1.0f + w);
}

// XCD-pinned jg2 schedule (assumes round-robin bid->XCD via bid&7): XCD x owns
// the 8 jg2 groups {x,15-x,16+x,31-x,32+x,47-x,48+x,63-x}. Work (nt*ks) per
// XCD is exactly 110 for every x; W1 slices are transposed by the consuming
// XCD so they are L2-warm. Per-XCD W1 working set ~1 MB < 4 MB L2.
__device__ __forceinline__ int jg2_of(int x, int cls) {
  switch (cls) {
    case 0: return x;
    case 1: return 15 - x;
    case 2: return 16 + x;
    case 3: return 31 - x;
    case 4: return 32 + x;
    case 5: return 47 - x;
    case 6: return 48 + x;
    default: return 63 - x;
  }
}

// ---------------------------------------------------------------------------
// Chunked k-major layout: tensor [row][k] stored as chunk(kq,row) =
// base + (kq*128 + row)*8 bf16 (16 B). MFMA fragment read = one
// global_load_dwordx4, 256 B contiguous per quad.
// ---------------------------------------------------------------------------
__device__ __forceinline__ void transpose_block_c(const float* __restrict__ src,
                                                  unsigned short* __restrict__ dst,
                                                  unsigned short* lds) {
  const int tid = threadIdx.x;
  const float4* s4 = (const float4*)src;
#pragma unroll
  for (int it = 0; it < 16; ++it) {
    int i4 = tid + it * 256;
    float4 v = s4[i4];
    int s = i4 >> 5;
    int t0 = (i4 * 4) & 127;
    int sc = s >> 3, se = s & 7;
#pragma unroll
    for (int e = 0; e < 4; ++e) {
      int t = t0 + e;
      lds[t * 136 + ((sc ^ ((t >> 2) & 7)) << 3) + se] = f2bf(((const float*)&v)[e]);
    }
  }
  __syncthreads();
#pragma unroll
  for (int it = 0; it < 8; ++it) {
    int c = tid + it * 256;
    int tr = c >> 4, sc = c & 15;
    uint4 d = *(const uint4*)(lds + tr * 136 + ((sc ^ ((tr >> 2) & 7)) << 3));
    *(uint4*)(dst + (sc * 128 + tr) * 8) = d;
  }
}

__global__ __launch_bounds__(256) void prepass_kernel(
    const float* __restrict__ W1, const float* __restrict__ trend2,
    const float* __restrict__ Wm1, const float* __restrict__ Wm2,
    unsigned short* __restrict__ W1Tc, unsigned short* __restrict__ T2c,
    unsigned short* __restrict__ Wm1c, unsigned short* __restrict__ Wm2c,
    float* __restrict__ out2) {
  __shared__ unsigned short lds[128 * 136];
  const int bid = blockIdx.x;
  if (bid < 256) {  // W1[stage][j][s][t] -> chunks (kq_s, t), XCD-pinned j map
    int x = bid & 7, r = bid >> 3;
    int stage = r >> 4, rr = r & 15;
    int j = jg2_of(x, rr >> 1) * 2 + (rr & 1);
    int blk = stage * 128 + j;
    transpose_block_c(W1 + blk * 16384, W1Tc + blk * 16384, lds);
  } else if (bid < 288) {  // trend2[b][s][h] -> chunks (kq_s, h) + fp32 copy
    const int b = bid - 256;
    transpose_block_c(trend2 + b * 16384, T2c + b * 16384, lds);
    const float4* s4 = (const float4*)(trend2 + b * 16384);
    float4* d4 = (float4*)(out2 + b * 16384);
#pragma unroll
    for (int it = 0; it < 16; ++it)
      d4[threadIdx.x + it * 256] = s4[threadIdx.x + it * 256];
  } else if (bid == 288) {
    transpose_block_c(Wm1, Wm1c, lds);
  } else {
    transpose_block_c(Wm2, Wm2c, lds);
  }
}

// ---------------------------------------------------------------------------
// Fused mix+MLP v3: block = (jg2 of 2 j, b), grid 2048, XCD-pinned.
// Lean k-loop: acc[2][4]=32 VGPR, 6 frags=24, psum=8 -> ~80 live, spill-free,
// allows 6 waves/SIMD residency (latency hiding via TLP, not manual prefetch).
//   Y = W1[j] x X^T (M=t, N=h, K=s, triangular-skipped);
//   res[h] = sum_t sigmoid-gelu(Y+b1)*W2;  x[j,h] = res + b2 + trend;
//   fused MLP on the 2 rows via padded 16-row MFMA tile.
// ---------------------------------------------------------------------------
__global__ __launch_bounds__(256, 4) void mix_fused_kernel(
    const unsigned short* __restrict__ XTc,   // [32] chunks (kq_s, h)
    const unsigned short* __restrict__ W1Tj,  // [128] chunks (kq_s, t), stage
    const float* __restrict__ b1j,            // [128][128] (j, t)
    const float* __restrict__ W2j,            // [128][128] (j, t)
    const float* __restrict__ b2j,            // [128]
    const float* __restrict__ trendR,         // [32][128][128] fp32 residual
    const unsigned short* __restrict__ Wm1c,  // chunks (kq_in, out)
    const unsigned short* __restrict__ Wm2c,
    const float* __restrict__ bm1,
    const float* __restrict__ bm2,
    float* __restrict__ outF,                 // [32][128][128] fp32 (MLP out)
    unsigned short* __restrict__ outTc,       // [32] chunks (kq_s, h) or null
    const int write_t) {
  __shared__ float res_ws[4][2][64];
  __shared__ __align__(16) unsigned short xa[16 * 128];  // MLP A-tile chunks
  __shared__ __align__(16) unsigned short U[16 * 128];   // GEMM1->2 bounce
  const int bid = blockIdx.x;
  const int x = bid & 7;
  const int i = bid >> 3;
  const int b = i & 31;
  const int jg = jg2_of(x, i >> 5);
  const int j0 = jg * 2;
  const int tid = threadIdx.x;
  const int wave = tid >> 6;
  const int lane = tid & 63;
  const int lane15 = lane & 15;
  const int quad = lane >> 4;

  {  // zero the padded tiles (rows 2-15 of xa must be 0 for the MFMA MLP)
    uint4 z = {0, 0, 0, 0};
    ((uint4*)xa)[tid] = z;
    ((uint4*)U)[tid] = z;
  }

  const int ntiles = (j0 >> 4) + 1;  // t-tiles with t <= j
  const int ksteps = (j0 >> 5) + 1;  // k 32-steps with s <= j
  const unsigned short* Bb = XTc + b * 16384;
  const unsigned short* A0 = W1Tj + j0 * 16384;
  const float C = -2.45546937f;  // -1.702 * log2(e)

#pragma unroll
  for (int p = 0; p < 2; ++p) {
    float psum[2][4];
#pragma unroll
    for (int jj = 0; jj < 2; ++jj)
#pragma unroll
      for (int ni = 0; ni < 4; ++ni) psum[jj][ni] = 0.f;

#pragma unroll
    for (int q = 0; q < 2; ++q) {
      const int mt = wave + q * 4;
      if (mt < ntiles) {
        const unsigned short* bp0 = Bb + (p * 64 + lane15) * 8;
        const unsigned short* ap0 = A0 + (mt * 16 + lane15) * 8;
        f32x4 acc[2][4];
#pragma unroll
        for (int jj = 0; jj < 2; ++jj)
#pragma unroll
          for (int ni = 0; ni < 4; ++ni) {
            f32x4 z = {0.f, 0.f, 0.f, 0.f};
            acc[jj][ni] = z;
          }
        for (int ks = 0; ks < ksteps; ++ks) {
          const int kq = ks * 4 + quad;
          bf16x8 a0 = *(const bf16x8*)(ap0 + kq * 1024);
          bf16x8 a1 = *(const bf16x8*)(ap0 + 16384 + kq * 1024);
          bf16x8 b0 = *(const bf16x8*)(bp0 + kq * 1024);
          bf16x8 b1 = *(const bf16x8*)(bp0 + kq * 1024 + 128);
          bf16x8 b2 = *(const bf16x8*)(bp0 + kq * 1024 + 256);
          bf16x8 b3 = *(const bf16x8*)(bp0 + kq * 1024 + 384);
          acc[0][0] = __builtin_amdgcn_mfma_f32_16x16x32_bf16(a0, b0, acc[0][0], 0, 0, 0);
          acc[1][0] = __builtin_amdgcn_mfma_f32_16x16x32_bf16(a1, b0, acc[1][0], 0, 0, 0);
          acc[0][1] = __builtin_amdgcn_mfma_f32_16x16x32_bf16(a0, b1, acc[0][1], 0, 0, 0);
          acc[1][1] = __builtin_amdgcn_mfma_f32_16x16x32_bf16(a1, b1, acc[1][1], 0, 0, 0);
          acc[0][2] = __builtin_amdgcn_mfma_f32_16x16x32_bf16(a0, b2, acc[0][2], 0, 0, 0);
          acc[1][2] = __builtin_amdgcn_mfma_f32_16x16x32_bf16(a1, b2, acc[1][2], 0, 0, 0);
          acc[0][3] = __builtin_amdgcn_mfma_f32_16x16x32_bf16(a0, b3, acc[0][3], 0, 0, 0);
          acc[1][3] = __builtin_amdgcn_mfma_f32_16x16x32_bf16(a1, b3, acc[1][3], 0, 0, 0);
        }
        const int tb = mt * 16 + quad * 4;
#pragma unroll
        for (int jj = 0; jj < 2; ++jj) {
          const int j = j0 + jj;
          float4 b1v = *(const float4*)(b1j + j * 128 + tb);
          float4 w2v = *(const float4*)(W2j + j * 128 + tb);
#pragma unroll
          for (int r = 0; r < 4; ++r) {
            float b1r = ((const float*)&b1v)[r];
            float w2r = ((const float*)&w2v)[r];
            float cb = C * b1r;
            float bw = b1r * w2r;
#pragma unroll
            for (int ni = 0; ni < 4; ++ni) {
              float a = acc[jj][ni][r];
              float m = __builtin_fmaf(a, C, cb);
              float e = fast_exp2(m);
              float rr2 = fast_rcp(1.0f + e);
              float yw = __builtin_fmaf(a, w2r, bw);
              psum[jj][ni] = __builtin_fmaf(yw, rr2, psum[jj][ni]);
            }
          }
        }
      }
    }
#pragma unroll
    for (int jj = 0; jj < 2; ++jj)
#pragma unroll
      for (int ni = 0; ni < 4; ++ni) {
        float v = psum[jj][ni];
        v += __shfl_xor(v, 16, 64);
        v += __shfl_xor(v, 32, 64);
        psum[jj][ni] = v;
      }
#pragma unroll
    for (int jj = 0; jj < 2; ++jj)
      res_ws[wave][jj][quad * 16 + lane15] = psum[jj][quad];
    __syncthreads();
    if (tid < 128) {  // combine + residual -> bf16 A-tile row jj, k=h chunks
      const int jj = tid >> 6;
      const int hh = tid & 63;
      const int j = j0 + jj;
      const int h = p * 64 + hh;
      float v = res_ws[0][jj][hh] + res_ws[1][jj][hh] +
                res_ws[2][jj][hh] + res_ws[3][jj][hh] +
                b2j[j] + trendR[(b * 128 + j) * 128 + h];
      xa[((h >> 3) * 16 + jj) * 8 + (h & 7)] = f2bf(v);
    }
    __syncthreads();
  }

  // ---- fused MLP on the block's 2 rows (16-row padded MFMA tile) ----
  f32x4 acc2[2];
  { f32x4 z = {0.f, 0.f, 0.f, 0.f}; acc2[0] = z; acc2[1] = z; }
#pragma unroll
  for (int ks = 0; ks < 4; ++ks) {  // GEMM1: x @ Wm1
    int kq = ks * 4 + quad;
    bf16x8 a = *(const bf16x8*)(xa + (kq * 16 + lane15) * 8);
    bf16x8 w0 = *(const bf16x8*)(Wm1c + (kq * 128 + (wave * 2 + 0) * 16 + lane15) * 8);
    bf16x8 w1 = *(const bf16x8*)(Wm1c + (kq * 128 + (wave * 2 + 1) * 16 + lane15) * 8);
    acc2[0] = __builtin_amdgcn_mfma_f32_16x16x32_bf16(a, w0, acc2[0], 0, 0, 0);
    acc2[1] = __builtin_amdgcn_mfma_f32_16x16x32_bf16(a, w1, acc2[1], 0, 0, 0);
  }
  if (quad == 0) {  // rows live in quad 0; bias+gelu -> U A-tile
#pragma unroll
    for (int nt = 0; nt < 2; ++nt) {
      int o = (wave * 2 + nt) * 16 + lane15;
      float bv = bm1[o];
#pragma unroll
      for (int r = 0; r < 2; ++r) {
        float g = gelu_f(acc2[nt][r] + bv);
        U[((o >> 3) * 16 + r) * 8 + (o & 7)] = f2bf(g);
      }
    }
  }
  __syncthreads();
  { f32x4 z = {0.f, 0.f, 0.f, 0.f}; acc2[0] = z; acc2[1] = z; }
#pragma unroll
  for (int ks = 0; ks < 4; ++ks) {  // GEMM2: u @ Wm2
    int kq = ks * 4 + quad;
    bf16x8 a = *(const bf16x8*)(U + (kq * 16 + lane15) * 8);
    bf16x8 w0 = *(const bf16x8*)(Wm2c + (kq * 128 + (wave * 2 + 0) * 16 + lane15) * 8);
    bf16x8 w1 = *(const bf16x8*)(Wm2c + (kq * 128 + (wave * 2 + 1) * 16 + lane15) * 8);
    acc2[0] = __builtin_amdgcn_mfma_f32_16x16x32_bf16(a, w0, acc2[0], 0, 0, 0);
    acc2[1] = __builtin_amdgcn_mfma_f32_16x16x32_bf16(a, w1, acc2[1], 0, 0, 0);
  }
  if (quad == 0) {  // epilogue: fp32 out + optional chunked bf16 (2 j's)
#pragma unroll
    for (int nt = 0; nt < 2; ++nt) {
      int o = (wave * 2 + nt) * 16 + lane15;
      float bv = bm2[o];
      unsigned short tmp2[2] __attribute__((aligned(4)));
#pragma unroll
      for (int r = 0; r < 2; ++r) {
        float v = acc2[nt][r] + bv;
        outF[b * 16384 + (j0 + r) * 128 + o] = v;
        tmp2[r] = f2bf(v);
      }
      if (write_t)
        *(unsigned*)(outTc + b * 16384 + ((j0 >> 3) * 128 + o) * 8 + (j0 & 7)) =
            *(const unsigned*)tmp2;
    }
  }
}

// ---------------------------------------------------------------------------
extern "C" void kernel_launch(void* const* d_in, const int* in_sizes, int n_in,
                              void* d_out, int out_size, void* d_ws, size_t ws_size,
                              hipStream_t stream) {
  (void)in_sizes; (void)n_in; (void)out_size; (void)ws_size;
  const float* trend0 = (const float*)d_in[0];
  const float* trend1 = (const float*)d_in[1];
  const float* trend2 = (const float*)d_in[2];
  const float* W1  = (const float*)d_in[3];
  const float* b1  = (const float*)d_in[4];
  const float* W2  = (const float*)d_in[5];
  const float* b2  = (const float*)d_in[6];
  const float* Wm1 = (const float*)d_in[7];
  const float* bm1 = (const float*)d_in[8];
  const float* Wm2 = (const float*)d_in[9];
  const float* bm2 = (const float*)d_in[10];
  float* out = (float*)d_out;
  char* ws = (char*)d_ws;

  unsigned short* W1Tc = (unsigned short*)(ws);             // 8.39 MB (2 stages)
  unsigned short* T2c  = (unsigned short*)(ws + 8388608);   // 1 MB
  unsigned short* A1Tc = (unsigned short*)(ws + 9437184);   // 1 MB
  unsigned short* Wm1c = (unsigned short*)(ws + 10485760);  // 32 KB
  unsigned short* Wm2c = (unsigned short*)(ws + 10518528);  // 32 KB

  // outputs: [A2 | A1 | trend2]
  prepass_kernel<<<290, 256, 0, stream>>>(W1, trend2, Wm1, Wm2,
                                          W1Tc, T2c, Wm1c, Wm2c, out + 2 * BSH);
  // stage 0: X = trend2, residual = trend1 -> A1 (d_out[1]) + A1Tc chunks
  mix_fused_kernel<<<2048, 256, 0, stream>>>(
      T2c, W1Tc, b1, W2, b2, trend1, Wm1c, Wm2c, bm1, bm2,
      out + BSH, A1Tc, 1);
  // stage 1: X = A1, residual = trend0 -> A2 (d_out[0])
  mix_fused_kernel<<<2048, 256, 0, stream>>>(
      A1Tc, W1Tc + 128 * 16384, b1 + 16384, W2 + 16384, b2 + 128, trend0,
      Wm1c, Wm2c, bm1, bm2, out, (unsigned short*)nullptr, 0);
}